// Round 3
// baseline (245.170 us; speedup 1.0000x reference)
//
#include <hip/hip_runtime.h>

#define B_TOTAL 131072
#define N 19
#define BB 13                  // batches per block (13*19 = 247 active threads of 256)
#define ROWS (BB * N)          // 247
#define NPAD 20                // padded row: 80 B, 16B-aligned rows for float4 LDS reads
#define OUT_PER_G (BB * N * N) // 4693 floats staged per block
#define NBLOCKS ((B_TOTAL + BB - 1) / BB)  // 10083 (last block: 6 valid batches)

// One block = 13 batches, one thread = one (batch, query-row i).
//   out[b,i,k] = feat[b,k] + bo[k] + invZ_i * sum_j exp(a_i*K_j - m_i)*V_j*Wo[k,j]
//   a_i = Q_i * (K . c) / T,  c[j] = mean_i corr[i,j]
// Register-pressure discipline (the round-3 change): no f[] live across
// phase 3 (residual re-read from feat_s via LDS broadcast), p[] overwrites
// V[] in place. Peak live set ~60 VGPR -> __launch_bounds__(256,4) holds
// WITHOUT spills; LDS 22 KB allows up to 7 blocks/CU.
__global__ void __launch_bounds__(256, 4) cga_kernel(
    const float* __restrict__ feats,
    const float* __restrict__ Wq, const float* __restrict__ bq,
    const float* __restrict__ Wk, const float* __restrict__ bk,
    const float* __restrict__ Wv, const float* __restrict__ bv,
    const float* __restrict__ Wo, const float* __restrict__ bo,
    const float* __restrict__ corr,
    const float* __restrict__ temp,
    float* __restrict__ out)
{
    __shared__ __align__(16) float feat_s[BB * NPAD];
    __shared__ __align__(16) float k_s[BB * NPAD];
    __shared__ __align__(16) float v_s[BB * NPAD];
    __shared__ __align__(16) float c_s[NPAD];
    __shared__ __align__(16) float out_s[OUT_PER_G];

    const int t  = threadIdx.x;
    const int b0 = blockIdx.x * BB;
    const int bl = t / N;          // local batch 0..12 (t < 247)
    const int i  = t - bl * N;     // query row 0..18
    const bool active = (t < ROWS);

    // ---- phase 1: stage features (coalesced) + correlation column means ----
    if (active) {
        int gidx = b0 * N + t;
        feat_s[bl * NPAD + i] = (gidx < B_TOTAL * N) ? feats[gidx] : 0.f;
    }
    if (t < N) {
        float s = 0.f;
#pragma unroll
        for (int r = 0; r < N; ++r) s += corr[r * N + t];
        c_s[t] = s * (1.0f / N);
    }
    const float invT = 1.0f / temp[0];
    __syncthreads();

    // ---- phase 2: Q/K/V projections (f[] live only inside this phase) ----
    float q_i = 0.f;
    if (active) {
        float f[NPAD];
        const float4* fp = (const float4*)(&feat_s[bl * NPAD]);
#pragma unroll
        for (int c4 = 0; c4 < 5; ++c4) {
            float4 x = fp[c4];
            f[c4*4+0] = x.x; f[c4*4+1] = x.y; f[c4*4+2] = x.z; f[c4*4+3] = x.w;
        }
        float k_i = bk[i], v_i = bv[i];
        q_i = bq[i];
#pragma unroll
        for (int j = 0; j < N; ++j) {
            q_i = fmaf(f[j], Wq[i * N + j], q_i);
            k_i = fmaf(f[j], Wk[i * N + j], k_i);
            v_i = fmaf(f[j], Wv[i * N + j], v_i);
        }
        k_s[bl * NPAD + i] = k_i;
        v_s[bl * NPAD + i] = v_i;
    }
    __syncthreads();

    // ---- phase 3: cw, softmax (in-place into V), Wo contraction ----
    if (active) {
        float K[NPAD], V[NPAD];
        const float4* kp = (const float4*)(&k_s[bl * NPAD]);
        const float4* vp = (const float4*)(&v_s[bl * NPAD]);
#pragma unroll
        for (int c4 = 0; c4 < 5; ++c4) {
            float4 x = kp[c4];
            K[c4*4+0] = x.x; K[c4*4+1] = x.y; K[c4*4+2] = x.z; K[c4*4+3] = x.w;
            float4 y = vp[c4];
            V[c4*4+0] = y.x; V[c4*4+1] = y.y; V[c4*4+2] = y.z; V[c4*4+3] = y.w;
        }
        float cw = 0.f;
#pragma unroll
        for (int j = 0; j < N; ++j) cw = fmaf(c_s[j], K[j], cw);
        const float a = q_i * cw * invT;

        float m = -1e30f;
#pragma unroll
        for (int j = 0; j < N; ++j) m = fmaxf(m, a * K[j]);
        float z = 0.f;
#pragma unroll
        for (int j = 0; j < N; ++j) {
            float e = __expf(fmaf(a, K[j], -m));
            z += e;
            V[j] *= e;             // V becomes p = e * V  (no extra array)
        }
        const float invZ = 1.0f / z;

        // contraction with Wo: wave-uniform addresses -> scalar loads + SGPR
        // FMA operands; residual re-read from feat_s (LDS broadcast, <=2-way)
        const int fb    = bl * NPAD;
        const int obase = t * N;
#pragma unroll
        for (int k = 0; k < N; ++k) {
            float acc = 0.f;
#pragma unroll
            for (int j = 0; j < N; ++j) acc = fmaf(V[j], Wo[k * N + j], acc);
            out_s[obase + k] = feat_s[fb + k] + bo[k] + acc * invZ;
        }
    }
    __syncthreads();

    // ---- phase 4: flat, fully-coalesced store of 13*361 staged floats ----
    const int outbase = b0 * (N * N);
#pragma unroll
    for (int r = 0; r < (OUT_PER_G + 255) / 256; ++r) {
        int idx = r * 256 + t;
        int go  = outbase + idx;
        if (idx < OUT_PER_G && go < B_TOTAL * N * N)
            out[go] = out_s[idx];
    }
}

extern "C" void kernel_launch(void* const* d_in, const int* in_sizes, int n_in,
                              void* d_out, int out_size, void* d_ws, size_t ws_size,
                              hipStream_t stream) {
    const float* feats = (const float*)d_in[0];
    const float* Wq    = (const float*)d_in[1];
    const float* bq    = (const float*)d_in[2];
    const float* Wk    = (const float*)d_in[3];
    const float* bk    = (const float*)d_in[4];
    const float* Wv    = (const float*)d_in[5];
    const float* bv    = (const float*)d_in[6];
    const float* Wo    = (const float*)d_in[7];
    const float* bo    = (const float*)d_in[8];
    const float* corr  = (const float*)d_in[9];
    const float* temp  = (const float*)d_in[10];
    float* out = (float*)d_out;

    cga_kernel<<<NBLOCKS, 256, 0, stream>>>(feats, Wq, bq, Wk, bk, Wv, bv,
                                            Wo, bo, corr, temp, out);
}